// Round 1
// baseline (24743.820 us; speedup 1.0000x reference)
//
#include <hip/hip_runtime.h>
#include <math.h>

constexpr int kB = 128, kT = 20, kH = 1024, kE = 512, kP = 36, kRaw = 2048, kV = 12000;
constexpr int kBM = 64, kBN = 64, kBK = 16;

struct Seg { const float* A; const float* W; int K; int lda; int ldw; };
struct GemmArgs {
  Seg seg[4];
  int nseg;
  const float* bias0;
  const float* bias1;
  float* C; int ldc; int M; int N; int act;
};

__device__ __forceinline__ float sigf(float x) { return 1.0f / (1.0f + expf(-x)); }

__global__ __launch_bounds__(256) void zero_f32(float* p, int n) {
  int i = blockIdx.x * 256 + threadIdx.x;
  if (i < n) p[i] = 0.0f;
}

// C[M,N] = act( sum_s A_s @ W_s + bias0 + bias1 )
// Requires: each seg.K % kBK == 0.
__global__ __launch_bounds__(256) void gemm_ms(GemmArgs ga) {
  __shared__ float As[kBK][kBM];
  __shared__ float Wt[kBK][kBN];
  const int bm = blockIdx.y * kBM;
  const int bn = blockIdx.x * kBN;
  const int tid = threadIdx.x;
  const int tx = tid & 15;   // -> n
  const int ty = tid >> 4;   // -> m
  float acc[4][4] = {};
  for (int s = 0; s < ga.nseg; ++s) {
    const float* __restrict__ A = ga.seg[s].A;
    const float* __restrict__ W = ga.seg[s].W;
    const int K = ga.seg[s].K, lda = ga.seg[s].lda, ldw = ga.seg[s].ldw;
    for (int k0 = 0; k0 < K; k0 += kBK) {
      #pragma unroll
      for (int i = 0; i < 4; ++i) {
        int idx = tid + i * 256;
        int m = idx >> 4, k = idx & 15;
        float v = 0.0f;
        if (bm + m < ga.M) v = A[(size_t)(bm + m) * lda + k0 + k];
        As[k][m] = v;
      }
      #pragma unroll
      for (int i = 0; i < 4; ++i) {
        int idx = tid + i * 256;
        int k = idx >> 6, n = idx & 63;
        float v = 0.0f;
        if (bn + n < ga.N) v = W[(size_t)(k0 + k) * ldw + bn + n];
        Wt[k][n] = v;
      }
      __syncthreads();
      #pragma unroll
      for (int k = 0; k < kBK; ++k) {
        float4 av = *reinterpret_cast<const float4*>(&As[k][ty * 4]);
        float4 wv = *reinterpret_cast<const float4*>(&Wt[k][tx * 4]);
        float a[4] = {av.x, av.y, av.z, av.w};
        float w[4] = {wv.x, wv.y, wv.z, wv.w};
        #pragma unroll
        for (int i = 0; i < 4; ++i)
          #pragma unroll
          for (int j = 0; j < 4; ++j) acc[i][j] = fmaf(a[i], w[j], acc[i][j]);
      }
      __syncthreads();
    }
  }
  #pragma unroll
  for (int i = 0; i < 4; ++i) {
    int m = bm + ty * 4 + i;
    if (m >= ga.M) continue;
    #pragma unroll
    for (int j = 0; j < 4; ++j) {
      int n = bn + tx * 4 + j;
      if (n >= ga.N) continue;
      float v = acc[i][j];
      if (ga.bias0) v += ga.bias0[n];
      if (ga.bias1) v += ga.bias1[n];
      if (ga.act == 1) v = fmaxf(v, 0.0f);
      ga.C[(size_t)m * ga.ldc + n] = v;
    }
  }
}

__global__ __launch_bounds__(256) void mean_p(const float* __restrict__ Vfeat,
                                              float* __restrict__ meanV) {
  int idx = blockIdx.x * 256 + threadIdx.x;
  if (idx >= kB * kH) return;
  int b = idx >> 10, h = idx & 1023;
  float sm = 0.0f;
  for (int p = 0; p < kP; ++p) sm += Vfeat[((size_t)b * kP + p) * kH + h];
  meanV[idx] = sm * (1.0f / kP);
}

__global__ __launch_bounds__(256) void gather_emb(const int* __restrict__ caps,
                                                  const float* __restrict__ emb,
                                                  float* __restrict__ wemb) {
  int idx = blockIdx.x * 256 + threadIdx.x;
  if (idx >= kB * kT * kE) return;
  int e = idx % kE;
  int bt = idx / kE;
  int t = bt % kT;
  int b = bt / kT;
  int tok = caps[b * (kT + 1) + t];
  wemb[idx] = emb[(size_t)tok * kE + e];
}

__global__ __launch_bounds__(256) void lstm1_elem(const float* __restrict__ g,
                                                  const float* __restrict__ sen,
                                                  float* __restrict__ c1, float* __restrict__ h1,
                                                  float* __restrict__ st) {
  int idx = blockIdx.x * 256 + threadIdx.x;
  if (idx >= kB * kH) return;
  int b = idx >> 10, h = idx & 1023;
  const float* gr = g + (size_t)b * 4 * kH;
  float ig = sigf(gr[h]);
  float fg = sigf(gr[kH + h]);
  float gg = tanhf(gr[2 * kH + h]);
  float og = sigf(gr[3 * kH + h]);
  float c = fg * c1[idx] + ig * gg;
  float hn = og * tanhf(c);
  c1[idx] = c;
  h1[idx] = hn;
  st[idx] = sigf(sen[idx]) * tanhf(c);
}

__global__ __launch_bounds__(256) void lstm2_elem(const float* __restrict__ g,
                                                  float* __restrict__ c2, float* __restrict__ h2,
                                                  const float* __restrict__ c_hat,
                                                  float* __restrict__ s_out) {
  int idx = blockIdx.x * 256 + threadIdx.x;
  if (idx >= kB * kH) return;
  int b = idx >> 10, h = idx & 1023;
  const float* gr = g + (size_t)b * 4 * kH;
  float ig = sigf(gr[h]);
  float fg = sigf(gr[kH + h]);
  float gg = tanhf(gr[2 * kH + h]);
  float og = sigf(gr[3 * kH + h]);
  float c = fg * c2[idx] + ig * gg;
  float hn = og * tanhf(c);
  c2[idx] = c;
  h2[idx] = hn;
  s_out[idx] = c_hat[idx] + hn;
}

// One block per batch element: ht_proj, st@Ws, z, softmax/alpha, att_vs, beta,
// context, c_hat, and alpha/beta output writes.
__global__ __launch_bounds__(256) void attn_step(
    const float* __restrict__ h1, const float* __restrict__ st,
    const float* __restrict__ img_proj, const float* __restrict__ Vfeat,
    const float* __restrict__ Wg, const float* __restrict__ Ws,
    const float* __restrict__ bs, const float* __restrict__ wh,
    float* __restrict__ c_hat, float* __restrict__ out_alphas,
    float* __restrict__ out_betas, int t) {
  const int b = blockIdx.x;
  const int tid = threadIdx.x;
  __shared__ float sh_h1[kH];
  __shared__ float sh_st[kH];
  __shared__ float htp[kP];
  __shared__ float stp[kP];
  __shared__ float zz[kP];
  __shared__ float alpha[kP];
  __shared__ float sred[2];
  for (int i = tid; i < kH; i += 256) {
    sh_h1[i] = h1[(size_t)b * kH + i];
    sh_st[i] = st[(size_t)b * kH + i];
  }
  __syncthreads();
  if (tid < kP) {
    float acc = 0.0f;
    for (int h = 0; h < kH; ++h) acc = fmaf(sh_h1[h], Wg[h * kP + tid], acc);
    htp[tid] = acc;
  } else if (tid >= 64 && tid < 64 + kP) {
    int j = tid - 64;
    float acc = 0.0f;
    for (int h = 0; h < kH; ++h) acc = fmaf(sh_st[h], Ws[h * kP + j], acc);
    stp[j] = acc;
  }
  __syncthreads();
  if (tid < kP) {
    const float* ip = img_proj + ((size_t)b * kP + tid) * kP;
    float acc = 0.0f;
    for (int j = 0; j < kP; ++j) acc = fmaf(tanhf(ip[j] + htp[j]), wh[j], acc);
    zz[tid] = acc;
  } else if (tid == 64) {
    float acc = 0.0f;
    for (int j = 0; j < kP; ++j) acc = fmaf(tanhf(stp[j] + bs[j] + htp[j]), wh[j], acc);
    sred[0] = acc;  // att_vs
  }
  __syncthreads();
  if (tid == 0) {
    float m = -1e30f;
    for (int p = 0; p < kP; ++p) m = fmaxf(m, zz[p]);
    float se = 0.0f;
    for (int p = 0; p < kP; ++p) { float e = expf(zz[p] - m); alpha[p] = e; se += e; }
    float inv = 1.0f / se;
    for (int p = 0; p < kP; ++p) alpha[p] *= inv;
    float av = sred[0];
    float m2 = fmaxf(m, av);
    float eb = expf(av - m2);
    float beta = eb / (se * expf(m - m2) + eb);
    sred[1] = beta;
    out_betas[b * kT + t] = beta;
  }
  __syncthreads();
  if (tid < kP) out_alphas[((size_t)b * kT + t) * kP + tid] = alpha[tid];
  const float beta = sred[1];
  for (int h = tid; h < kH; h += 256) {
    float ctx = 0.0f;
    for (int p = 0; p < kP; ++p) ctx = fmaf(alpha[p], Vfeat[((size_t)b * kP + p) * kH + h], ctx);
    c_hat[(size_t)b * kH + h] = beta * sh_st[h] + (1.0f - beta) * ctx;
  }
}

extern "C" void kernel_launch(void* const* d_in, const int* in_sizes, int n_in,
                              void* d_out, int out_size, void* d_ws, size_t ws_size,
                              hipStream_t stream) {
  const float* images  = (const float*)d_in[0];
  const int*   caps    = (const int*)d_in[1];
  // d_in[2] = caption_lengths (scalar 21) -> T = 20, hardcoded
  const float* W_img   = (const float*)d_in[3];
  const float* b_img   = (const float*)d_in[4];
  const float* W_glob  = (const float*)d_in[5];
  const float* b_glob  = (const float*)d_in[6];
  const float* W_ih1   = (const float*)d_in[7];
  const float* W_hh1   = (const float*)d_in[8];
  const float* b_ih1   = (const float*)d_in[9];
  const float* b_hh1   = (const float*)d_in[10];
  const float* Wx_gate = (const float*)d_in[11];
  const float* bx_gate = (const float*)d_in[12];
  const float* Wh_gate = (const float*)d_in[13];
  const float* bh_gate = (const float*)d_in[14];
  const float* W_ih2   = (const float*)d_in[15];
  const float* W_hh2   = (const float*)d_in[16];
  const float* b_ih2   = (const float*)d_in[17];
  const float* b_hh2   = (const float*)d_in[18];
  const float* Wv      = (const float*)d_in[19];
  const float* bv      = (const float*)d_in[20];
  const float* Ws_     = (const float*)d_in[21];
  const float* bs_     = (const float*)d_in[22];
  const float* Wg      = (const float*)d_in[23];
  const float* wh      = (const float*)d_in[24];
  const float* emb     = (const float*)d_in[25];
  const float* W_fc    = (const float*)d_in[26];
  const float* b_fc    = (const float*)d_in[27];

  float* out = (float*)d_out;
  float* out_alphas = out + (size_t)kB * kT * kV;
  float* out_betas  = out_alphas + (size_t)kB * kT * kP;

  float* ws = (float*)d_ws;
  float* Vfeat    = ws; ws += (size_t)kB * kP * kH;   // 4,718,592
  float* wemb     = ws; ws += (size_t)kB * kT * kE;   // 1,310,720
  float* img_proj = ws; ws += (size_t)kB * kP * kP;   //   165,888
  float* glob     = ws; ws += (size_t)kB * kE;        //    65,536
  float* h1   = ws; ws += kB * kH;
  float* c1   = ws; ws += kB * kH;
  float* h2   = ws; ws += kB * kH;
  float* c2   = ws; ws += kB * kH;
  float* gbuf = ws; ws += kB * 4 * kH;                //  also meanV
  float* sen  = ws; ws += kB * kH;
  float* st   = ws; ws += kB * kH;
  float* chat = ws; ws += kB * kH;
  float* sbuf = ws; ws += kB * kH;

  auto launch_gemm = [&](GemmArgs ga) {
    dim3 grid((ga.N + kBN - 1) / kBN, (ga.M + kBM - 1) / kBM);
    gemm_ms<<<grid, dim3(256), 0, stream>>>(ga);
  };

  // zero LSTM state (h1,c1,h2,c2 contiguous)
  zero_f32<<<(4 * kB * kH + 255) / 256, 256, 0, stream>>>(h1, 4 * kB * kH);

  // Vfeat = relu(images @ W_img + b_img)
  {
    GemmArgs ga = {};
    ga.seg[0] = {images, W_img, kRaw, kRaw, kH};
    ga.nseg = 1; ga.bias0 = b_img; ga.bias1 = nullptr;
    ga.C = Vfeat; ga.ldc = kH; ga.M = kB * kP; ga.N = kH; ga.act = 1;
    launch_gemm(ga);
  }
  // meanV (into gbuf)
  mean_p<<<(kB * kH + 255) / 256, 256, 0, stream>>>(Vfeat, gbuf);
  // glob = relu(meanV @ W_glob + b_glob)
  {
    GemmArgs ga = {};
    ga.seg[0] = {gbuf, W_glob, kH, kH, kE};
    ga.nseg = 1; ga.bias0 = b_glob;
    ga.C = glob; ga.ldc = kE; ga.M = kB; ga.N = kE; ga.act = 1;
    launch_gemm(ga);
  }
  // img_proj = Vfeat @ Wv + bv
  {
    GemmArgs ga = {};
    ga.seg[0] = {Vfeat, Wv, kH, kH, kP};
    ga.nseg = 1; ga.bias0 = bv;
    ga.C = img_proj; ga.ldc = kP; ga.M = kB * kP; ga.N = kP; ga.act = 0;
    launch_gemm(ga);
  }
  // word embeddings gather
  gather_emb<<<(kB * kT * kE + 255) / 256, 256, 0, stream>>>(caps, emb, wemb);

  for (int t = 0; t < kT; ++t) {
    // g1 = [h2|glob|we_t] @ W_ih1 + h1 @ W_hh1 + b_ih1 + b_hh1
    {
      GemmArgs ga = {};
      ga.seg[0] = {h2, W_ih1, kH, kH, 4 * kH};
      ga.seg[1] = {glob, W_ih1 + (size_t)kH * 4 * kH, kE, kE, 4 * kH};
      ga.seg[2] = {wemb + (size_t)t * kE, W_ih1 + (size_t)(kH + kE) * 4 * kH, kE, kT * kE, 4 * kH};
      ga.seg[3] = {h1, W_hh1, kH, kH, 4 * kH};
      ga.nseg = 4; ga.bias0 = b_ih1; ga.bias1 = b_hh1;
      ga.C = gbuf; ga.ldc = 4 * kH; ga.M = kB; ga.N = 4 * kH; ga.act = 0;
      launch_gemm(ga);
    }
    // sen_pre = [h2|glob|we_t] @ Wx_gate + h1 @ Wh_gate + bx + bh
    {
      GemmArgs ga = {};
      ga.seg[0] = {h2, Wx_gate, kH, kH, kH};
      ga.seg[1] = {glob, Wx_gate + (size_t)kH * kH, kE, kE, kH};
      ga.seg[2] = {wemb + (size_t)t * kE, Wx_gate + (size_t)(kH + kE) * kH, kE, kT * kE, kH};
      ga.seg[3] = {h1, Wh_gate, kH, kH, kH};
      ga.nseg = 4; ga.bias0 = bx_gate; ga.bias1 = bh_gate;
      ga.C = sen; ga.ldc = kH; ga.M = kB; ga.N = kH; ga.act = 0;
      launch_gemm(ga);
    }
    lstm1_elem<<<(kB * kH + 255) / 256, 256, 0, stream>>>(gbuf, sen, c1, h1, st);
    attn_step<<<kB, 256, 0, stream>>>(h1, st, img_proj, Vfeat, Wg, Ws_, bs_, wh,
                                      chat, out_alphas, out_betas, t);
    // g2 = [c_hat|h1n] @ W_ih2 + h2 @ W_hh2 + b_ih2 + b_hh2
    {
      GemmArgs ga = {};
      ga.seg[0] = {chat, W_ih2, kH, kH, 4 * kH};
      ga.seg[1] = {h1, W_ih2 + (size_t)kH * 4 * kH, kH, kH, 4 * kH};
      ga.seg[2] = {h2, W_hh2, kH, kH, 4 * kH};
      ga.nseg = 3; ga.bias0 = b_ih2; ga.bias1 = b_hh2;
      ga.C = gbuf; ga.ldc = 4 * kH; ga.M = kB; ga.N = 4 * kH; ga.act = 0;
      launch_gemm(ga);
    }
    lstm2_elem<<<(kB * kH + 255) / 256, 256, 0, stream>>>(gbuf, c2, h2, chat, sbuf);
    // preds[:, t, :] = (c_hat + h2n) @ W_fc + b_fc
    {
      GemmArgs ga = {};
      ga.seg[0] = {sbuf, W_fc, kH, kH, kV};
      ga.nseg = 1; ga.bias0 = b_fc;
      ga.C = out + (size_t)t * kV; ga.ldc = kT * kV; ga.M = kB; ga.N = kV; ga.act = 0;
      launch_gemm(ga);
    }
  }
}

// Round 2
// 3260.430 us; speedup vs baseline: 7.5891x; 7.5891x over previous
//
#include <hip/hip_runtime.h>
#include <hip/hip_bf16.h>
#include <math.h>

typedef __attribute__((ext_vector_type(4))) float f32x4;
typedef __attribute__((ext_vector_type(8))) short bf16x8;

constexpr int kB = 128, kT = 20, kH = 1024, kE = 512, kP = 36, kRaw = 2048, kV = 12000;
constexpr int kBM = 64, kBN = 64, kBK = 16;  // fp32 gemm_ms tiles

__device__ __forceinline__ float sigf(float x) { return 1.0f / (1.0f + expf(-x)); }

// ---------------------------------------------------------------- utilities
__global__ __launch_bounds__(256) void zero_f32(float* p, int n) {
  int i = blockIdx.x * 256 + threadIdx.x;
  if (i < n) p[i] = 0.0f;
}
__global__ __launch_bounds__(256) void zero_bf16(__hip_bfloat16* p, int n) {
  int i = blockIdx.x * 256 + threadIdx.x;
  if (i < n) p[i] = __float2bfloat16(0.0f);
}
__global__ __launch_bounds__(256) void f32_to_bf16(const float* __restrict__ src,
                                                   __hip_bfloat16* __restrict__ dst, int n4) {
  int i = blockIdx.x * 256 + threadIdx.x;
  if (i >= n4) return;
  float4 v = reinterpret_cast<const float4*>(src)[i];
  __hip_bfloat16* d = dst + (size_t)i * 4;
  d[0] = __float2bfloat16(v.x); d[1] = __float2bfloat16(v.y);
  d[2] = __float2bfloat16(v.z); d[3] = __float2bfloat16(v.w);
}

// dst[n + n_off][k + k_off] = bf16(src[k][n]);  src is [Kblk][ld_src]
__global__ __launch_bounds__(256) void transpose_to_bf16(const float* __restrict__ src, int ld_src,
                                                         int Kblk, int Nblk,
                                                         __hip_bfloat16* __restrict__ dst, int lddst,
                                                         int k_off, int n_off) {
  __shared__ float t[32][33];
  int n0 = blockIdx.x * 32, k0 = blockIdx.y * 32;
  int tx = threadIdx.x & 31, ty = threadIdx.x >> 5;  // 32 x 8
  #pragma unroll
  for (int i = 0; i < 32; i += 8) {
    int k = k0 + ty + i, n = n0 + tx;
    t[ty + i][tx] = (k < Kblk && n < Nblk) ? src[(size_t)k * ld_src + n] : 0.0f;
  }
  __syncthreads();
  #pragma unroll
  for (int i = 0; i < 32; i += 8) {
    int n = n0 + ty + i, k = k0 + tx;
    if (n < Nblk && k < Kblk)
      dst[(size_t)(n + n_off) * lddst + k + k_off] = __float2bfloat16(t[tx][ty + i]);
  }
}

__global__ __launch_bounds__(256) void pack_biases(const float* b_ih1, const float* b_hh1,
                                                   const float* bx, const float* bh,
                                                   const float* b_ih2, const float* b_hh2,
                                                   float* bias_g1, float* bias_g2) {
  int i = blockIdx.x * 256 + threadIdx.x;
  if (i < 4096) {
    bias_g1[i] = b_ih1[i] + b_hh1[i];
    bias_g2[i] = b_ih2[i] + b_hh2[i];
  } else if (i < 5120) {
    bias_g1[i] = bx[i - 4096] + bh[i - 4096];
  }
}

// ------------------------------------------------------- bf16 MFMA GEMM
// C[M,N] (fp32) = act( concat_K(A_segs) @ WT^T + bias ), WT is [N][K] bf16.
// M, Ktot, seg boundaries all multiples of 64. N bound-checked on write only
// (WT must be padded to a multiple of 64 rows).
struct SegB { const __hip_bfloat16* A; int lda; int kstart; int kend; };
struct GemmBArgs {
  SegB seg[4]; int nseg;
  const __hip_bfloat16* WT; int ldk;
  const float* bias;
  float* C; int ldc; int N; int Ktot; int act;
};

#define AS1C const __attribute__((address_space(1))) void*
#define AS3P __attribute__((address_space(3))) void*

__global__ __launch_bounds__(256) void gemm_bf16(GemmBArgs ga) {
  __shared__ __hip_bfloat16 lds[8192];  // A: bytes [0,8192)  B: [8192,16384)
  const int bm = blockIdx.y * 64;
  const int bn = blockIdx.x * 64;
  const int tid = threadIdx.x;
  const int lane = tid & 63;
  const int w = tid >> 6;
  const int wr = w >> 1, wc = w & 1;

  // staging geometry: round r covers LDS bytes [(r*4+w)*1024 + lane*16 ...)
  int rowS[2], cbsS[2], ldsoff[2];
  #pragma unroll
  for (int r = 0; r < 2; ++r) {
    int off = ((r * 4 + w) * 64 + lane) * 16;  // linear byte in 8 KB half
    rowS[r] = off >> 7;                        // row (stride 128 B)
    cbsS[r] = (off & 127) ^ ((rowS[r] & 7) << 4);  // inverse-swizzled col byte
    ldsoff[r] = (r * 4 + w) * 1024;            // wave-uniform LDS base
  }

  f32x4 acc[2][2] = {};

  int si = 0;
  for (int k0 = 0; k0 < ga.Ktot; k0 += 64) {
    while (k0 >= ga.seg[si].kend) ++si;
    const __hip_bfloat16* Aseg = ga.seg[si].A;
    const int lda = ga.seg[si].lda;
    const int ks = k0 - ga.seg[si].kstart;
    #pragma unroll
    for (int r = 0; r < 2; ++r) {
      const __hip_bfloat16* srcA = Aseg + (size_t)(bm + rowS[r]) * lda + ks + (cbsS[r] >> 1);
      __builtin_amdgcn_global_load_lds((AS1C)srcA, (AS3P)((char*)lds + ldsoff[r]), 16, 0, 0);
      const __hip_bfloat16* srcB = ga.WT + (size_t)(bn + rowS[r]) * ga.ldk + k0 + (cbsS[r] >> 1);
      __builtin_amdgcn_global_load_lds((AS1C)srcB, (AS3P)((char*)lds + 8192 + ldsoff[r]), 16, 0, 0);
    }
    __syncthreads();  // drains vmcnt -> LDS tiles ready
    const char* ldsA = (const char*)lds;
    const char* ldsB = (const char*)lds + 8192;
    #pragma unroll
    for (int kk = 0; kk < 2; ++kk) {
      bf16x8 a[2], b[2];
      #pragma unroll
      for (int f = 0; f < 2; ++f) {
        int row = wr * 32 + f * 16 + (lane & 15);
        int byt = row * 128 + ((kk * 64 + (lane >> 4) * 16) ^ ((row & 7) << 4));
        a[f] = *(const bf16x8*)(ldsA + byt);
        int nl = wc * 32 + f * 16 + (lane & 15);
        int bbyt = nl * 128 + ((kk * 64 + (lane >> 4) * 16) ^ ((nl & 7) << 4));
        b[f] = *(const bf16x8*)(ldsB + bbyt);
      }
      #pragma unroll
      for (int fm = 0; fm < 2; ++fm)
        #pragma unroll
        for (int fn = 0; fn < 2; ++fn)
          acc[fm][fn] = __builtin_amdgcn_mfma_f32_16x16x32_bf16(a[fm], b[fn], acc[fm][fn], 0, 0, 0);
    }
    __syncthreads();
  }

  #pragma unroll
  for (int fm = 0; fm < 2; ++fm) {
    int rbase = bm + wr * 32 + fm * 16 + (lane >> 4) * 4;
    #pragma unroll
    for (int fn = 0; fn < 2; ++fn) {
      int col = bn + wc * 32 + fn * 16 + (lane & 15);
      if (col >= ga.N) continue;
      float bv = ga.bias ? ga.bias[col] : 0.0f;
      #pragma unroll
      for (int j = 0; j < 4; ++j) {
        float v = acc[fm][fn][j] + bv;
        if (ga.act == 1) v = fmaxf(v, 0.0f);
        ga.C[(size_t)(rbase + j) * ga.ldc + col] = v;
      }
    }
  }
}

// ------------------------------------------------------- fp32 GEMM (small, rare)
struct Seg { const float* A; const float* W; int K; int lda; int ldw; };
struct GemmArgs {
  Seg seg[4];
  int nseg;
  const float* bias0;
  const float* bias1;
  float* C; __hip_bfloat16* C16; int ldc; int M; int N; int act;
};

__global__ __launch_bounds__(256) void gemm_ms(GemmArgs ga) {
  __shared__ float As[kBK][kBM];
  __shared__ float Wt[kBK][kBN];
  const int bm = blockIdx.y * kBM;
  const int bn = blockIdx.x * kBN;
  const int tid = threadIdx.x;
  const int tx = tid & 15;
  const int ty = tid >> 4;
  float acc[4][4] = {};
  for (int s = 0; s < ga.nseg; ++s) {
    const float* __restrict__ A = ga.seg[s].A;
    const float* __restrict__ W = ga.seg[s].W;
    const int K = ga.seg[s].K, lda = ga.seg[s].lda, ldw = ga.seg[s].ldw;
    for (int k0 = 0; k0 < K; k0 += kBK) {
      #pragma unroll
      for (int i = 0; i < 4; ++i) {
        int idx = tid + i * 256;
        int m = idx >> 4, k = idx & 15;
        float v = 0.0f;
        if (bm + m < ga.M) v = A[(size_t)(bm + m) * lda + k0 + k];
        As[k][m] = v;
      }
      #pragma unroll
      for (int i = 0; i < 4; ++i) {
        int idx = tid + i * 256;
        int k = idx >> 6, n = idx & 63;
        float v = 0.0f;
        if (bn + n < ga.N) v = W[(size_t)(k0 + k) * ldw + bn + n];
        Wt[k][n] = v;
      }
      __syncthreads();
      #pragma unroll
      for (int k = 0; k < kBK; ++k) {
        float4 av = *reinterpret_cast<const float4*>(&As[k][ty * 4]);
        float4 wv = *reinterpret_cast<const float4*>(&Wt[k][tx * 4]);
        float a[4] = {av.x, av.y, av.z, av.w};
        float wv2[4] = {wv.x, wv.y, wv.z, wv.w};
        #pragma unroll
        for (int i = 0; i < 4; ++i)
          #pragma unroll
          for (int j = 0; j < 4; ++j) acc[i][j] = fmaf(a[i], wv2[j], acc[i][j]);
      }
      __syncthreads();
    }
  }
  #pragma unroll
  for (int i = 0; i < 4; ++i) {
    int m = bm + ty * 4 + i;
    if (m >= ga.M) continue;
    #pragma unroll
    for (int j = 0; j < 4; ++j) {
      int n = bn + tx * 4 + j;
      if (n >= ga.N) continue;
      float v = acc[i][j];
      if (ga.bias0) v += ga.bias0[n];
      if (ga.bias1) v += ga.bias1[n];
      if (ga.act == 1) v = fmaxf(v, 0.0f);
      ga.C[(size_t)m * ga.ldc + n] = v;
      if (ga.C16) ga.C16[(size_t)m * ga.ldc + n] = __float2bfloat16(v);
    }
  }
}

// ------------------------------------------------------- small fused kernels
__global__ __launch_bounds__(256) void mean_p(const float* __restrict__ Vfeat,
                                              float* __restrict__ meanV) {
  int idx = blockIdx.x * 256 + threadIdx.x;
  if (idx >= kB * kH) return;
  int b = idx >> 10, h = idx & 1023;
  float sm = 0.0f;
  for (int p = 0; p < kP; ++p) sm += Vfeat[((size_t)b * kP + p) * kH + h];
  meanV[idx] = sm * (1.0f / kP);
}

__global__ __launch_bounds__(256) void gather_emb(const int* __restrict__ caps,
                                                  const float* __restrict__ emb,
                                                  __hip_bfloat16* __restrict__ wembb) {
  int idx = blockIdx.x * 256 + threadIdx.x;
  if (idx >= kB * kT * kE) return;
  int e = idx % kE;
  int bt = idx / kE;
  int t = bt % kT;
  int b = bt / kT;
  int tok = caps[b * (kT + 1) + t];
  wembb[idx] = __float2bfloat16(emb[(size_t)tok * kE + e]);
}

// g layout: [b][5120] = 4096 gates + 1024 sentinel preact
__global__ __launch_bounds__(256) void lstm1_elem(const float* __restrict__ g,
                                                  float* __restrict__ c1, float* __restrict__ h1,
                                                  __hip_bfloat16* __restrict__ h1b,
                                                  float* __restrict__ st) {
  int idx = blockIdx.x * 256 + threadIdx.x;
  if (idx >= kB * kH) return;
  int b = idx >> 10, h = idx & 1023;
  const float* gr = g + (size_t)b * 5120;
  float ig = sigf(gr[h]);
  float fg = sigf(gr[kH + h]);
  float gg = tanhf(gr[2 * kH + h]);
  float og = sigf(gr[3 * kH + h]);
  float c = fg * c1[idx] + ig * gg;
  float hn = og * tanhf(c);
  c1[idx] = c;
  h1[idx] = hn;
  h1b[idx] = __float2bfloat16(hn);
  st[idx] = sigf(gr[4 * kH + h]) * tanhf(c);
}

// g layout: [b][4096]
__global__ __launch_bounds__(256) void lstm2_elem(const float* __restrict__ g,
                                                  float* __restrict__ c2, float* __restrict__ h2,
                                                  __hip_bfloat16* __restrict__ h2b,
                                                  const float* __restrict__ c_hat,
                                                  __hip_bfloat16* __restrict__ sbufb) {
  int idx = blockIdx.x * 256 + threadIdx.x;
  if (idx >= kB * kH) return;
  int b = idx >> 10, h = idx & 1023;
  const float* gr = g + (size_t)b * 4 * kH;
  float ig = sigf(gr[h]);
  float fg = sigf(gr[kH + h]);
  float gg = tanhf(gr[2 * kH + h]);
  float og = sigf(gr[3 * kH + h]);
  float c = fg * c2[idx] + ig * gg;
  float hn = og * tanhf(c);
  c2[idx] = c;
  h2[idx] = hn;
  h2b[idx] = __float2bfloat16(hn);
  sbufb[idx] = __float2bfloat16(c_hat[idx] + hn);
}

__global__ __launch_bounds__(256) void attn_step(
    const float* __restrict__ h1, const float* __restrict__ st,
    const float* __restrict__ img_proj, const float* __restrict__ Vfeat,
    const float* __restrict__ Wg, const float* __restrict__ Ws,
    const float* __restrict__ bs, const float* __restrict__ wh,
    float* __restrict__ c_hat, __hip_bfloat16* __restrict__ c_hatb,
    float* __restrict__ out_alphas, float* __restrict__ out_betas, int t) {
  const int b = blockIdx.x;
  const int tid = threadIdx.x;
  __shared__ float sh_h1[kH];
  __shared__ float sh_st[kH];
  __shared__ float htp[kP];
  __shared__ float stp[kP];
  __shared__ float zz[kP];
  __shared__ float alpha[kP];
  __shared__ float sred[2];
  for (int i = tid; i < kH; i += 256) {
    sh_h1[i] = h1[(size_t)b * kH + i];
    sh_st[i] = st[(size_t)b * kH + i];
  }
  __syncthreads();
  if (tid < kP) {
    float acc = 0.0f;
    for (int h = 0; h < kH; ++h) acc = fmaf(sh_h1[h], Wg[h * kP + tid], acc);
    htp[tid] = acc;
  } else if (tid >= 64 && tid < 64 + kP) {
    int j = tid - 64;
    float acc = 0.0f;
    for (int h = 0; h < kH; ++h) acc = fmaf(sh_st[h], Ws[h * kP + j], acc);
    stp[j] = acc;
  }
  __syncthreads();
  if (tid < kP) {
    const float* ip = img_proj + ((size_t)b * kP + tid) * kP;
    float acc = 0.0f;
    for (int j = 0; j < kP; ++j) acc = fmaf(tanhf(ip[j] + htp[j]), wh[j], acc);
    zz[tid] = acc;
  } else if (tid == 64) {
    float acc = 0.0f;
    for (int j = 0; j < kP; ++j) acc = fmaf(tanhf(stp[j] + bs[j] + htp[j]), wh[j], acc);
    sred[0] = acc;  // att_vs
  }
  __syncthreads();
  if (tid == 0) {
    float m = -1e30f;
    for (int p = 0; p < kP; ++p) m = fmaxf(m, zz[p]);
    float se = 0.0f;
    for (int p = 0; p < kP; ++p) { float e = expf(zz[p] - m); alpha[p] = e; se += e; }
    float inv = 1.0f / se;
    for (int p = 0; p < kP; ++p) alpha[p] *= inv;
    float av = sred[0];
    float m2 = fmaxf(m, av);
    float eb = expf(av - m2);
    float beta = eb / (se * expf(m - m2) + eb);
    sred[1] = beta;
    out_betas[b * kT + t] = beta;
  }
  __syncthreads();
  if (tid < kP) out_alphas[((size_t)b * kT + t) * kP + tid] = alpha[tid];
  const float beta = sred[1];
  for (int h = tid; h < kH; h += 256) {
    float ctx = 0.0f;
    for (int p = 0; p < kP; ++p) ctx = fmaf(alpha[p], Vfeat[((size_t)b * kP + p) * kH + h], ctx);
    float v = beta * sh_st[h] + (1.0f - beta) * ctx;
    c_hat[(size_t)b * kH + h] = v;
    c_hatb[(size_t)b * kH + h] = __float2bfloat16(v);
  }
}

// ------------------------------------------------------------------ launch
extern "C" void kernel_launch(void* const* d_in, const int* in_sizes, int n_in,
                              void* d_out, int out_size, void* d_ws, size_t ws_size,
                              hipStream_t stream) {
  const float* images  = (const float*)d_in[0];
  const int*   caps    = (const int*)d_in[1];
  const float* W_img   = (const float*)d_in[3];
  const float* b_img   = (const float*)d_in[4];
  const float* W_glob  = (const float*)d_in[5];
  const float* b_glob  = (const float*)d_in[6];
  const float* W_ih1   = (const float*)d_in[7];
  const float* W_hh1   = (const float*)d_in[8];
  const float* b_ih1   = (const float*)d_in[9];
  const float* b_hh1   = (const float*)d_in[10];
  const float* Wx_gate = (const float*)d_in[11];
  const float* bx_gate = (const float*)d_in[12];
  const float* Wh_gate = (const float*)d_in[13];
  const float* bh_gate = (const float*)d_in[14];
  const float* W_ih2   = (const float*)d_in[15];
  const float* W_hh2   = (const float*)d_in[16];
  const float* b_ih2   = (const float*)d_in[17];
  const float* b_hh2   = (const float*)d_in[18];
  const float* Wv      = (const float*)d_in[19];
  const float* bv      = (const float*)d_in[20];
  const float* Ws_     = (const float*)d_in[21];
  const float* bs_     = (const float*)d_in[22];
  const float* Wg      = (const float*)d_in[23];
  const float* wh      = (const float*)d_in[24];
  const float* emb     = (const float*)d_in[25];
  const float* W_fc    = (const float*)d_in[26];
  const float* b_fc    = (const float*)d_in[27];

  float* out = (float*)d_out;
  float* out_alphas = out + (size_t)kB * kT * kV;
  float* out_betas  = out_alphas + (size_t)kB * kT * kP;

  char* base = (char*)d_ws;
  auto alloc = [&](size_t bytes) {
    char* p = base;
    base += (bytes + 255) & ~(size_t)255;
    return p;
  };
  float*          Vfeat   = (float*)alloc((size_t)kB * kP * kH * 4);
  __hip_bfloat16* imagesb = (__hip_bfloat16*)alloc((size_t)kB * kP * kRaw * 2);
  __hip_bfloat16* WTg1    = (__hip_bfloat16*)alloc((size_t)5120 * 3072 * 2);
  __hip_bfloat16* WTg2    = (__hip_bfloat16*)alloc((size_t)4096 * 3072 * 2);
  __hip_bfloat16* WTfc    = (__hip_bfloat16*)alloc((size_t)12032 * 1024 * 2);
  __hip_bfloat16* WTimg   = (__hip_bfloat16*)alloc((size_t)1024 * 2048 * 2);
  __hip_bfloat16* wembb   = (__hip_bfloat16*)alloc((size_t)kB * kT * kE * 2);
  float*          img_proj= (float*)alloc((size_t)kB * kP * kP * 4);
  float*          glob    = (float*)alloc((size_t)kB * kE * 4);
  __hip_bfloat16* globb   = (__hip_bfloat16*)alloc((size_t)kB * kE * 2);
  float*          meanV   = (float*)alloc((size_t)kB * kH * 4);
  float*          h1      = (float*)alloc((size_t)4 * kB * kH * 4);  // h1,c1,h2,c2
  float*          c1      = h1 + kB * kH;
  float*          h2      = c1 + kB * kH;
  float*          c2      = h2 + kB * kH;
  __hip_bfloat16* h1b     = (__hip_bfloat16*)alloc((size_t)2 * kB * kH * 2);
  __hip_bfloat16* h2b     = h1b + kB * kH;
  float*          g1out   = (float*)alloc((size_t)kB * 5120 * 4);
  float*          st      = (float*)alloc((size_t)kB * kH * 4);
  float*          chat    = (float*)alloc((size_t)kB * kH * 4);
  __hip_bfloat16* chatb   = (__hip_bfloat16*)alloc((size_t)kB * kH * 2);
  __hip_bfloat16* sbufb   = (__hip_bfloat16*)alloc((size_t)kB * kH * 2);
  float*          bias_g1 = (float*)alloc(5120 * 4);
  float*          bias_g2 = (float*)alloc(4096 * 4);

  // ---- once-per-call prep
  zero_f32<<<(4 * kB * kH + 255) / 256, 256, 0, stream>>>(h1, 4 * kB * kH);
  zero_bf16<<<(2 * kB * kH + 255) / 256, 256, 0, stream>>>(h1b, 2 * kB * kH);
  {
    int n4 = kB * kP * kRaw / 4;
    f32_to_bf16<<<(n4 + 255) / 256, 256, 0, stream>>>(images, imagesb, n4);
  }
  auto T = [&](const float* src, int ldsrc, int K, int N, __hip_bfloat16* dst, int lddst,
               int koff, int noff) {
    transpose_to_bf16<<<dim3((N + 31) / 32, (K + 31) / 32), 256, 0, stream>>>(
        src, ldsrc, K, N, dst, lddst, koff, noff);
  };
  T(W_img,   kH,     kRaw, kH,     WTimg, kRaw, 0, 0);
  T(W_ih1,   4 * kH, 2048, 4 * kH, WTg1,  3072, 0, 0);
  T(W_hh1,   4 * kH, 1024, 4 * kH, WTg1,  3072, 2048, 0);
  T(Wx_gate, kH,     2048, kH,     WTg1,  3072, 0, 4096);
  T(Wh_gate, kH,     1024, kH,     WTg1,  3072, 2048, 4096);
  T(W_ih2,   4 * kH, 2048, 4 * kH, WTg2,  3072, 0, 0);
  T(W_hh2,   4 * kH, 1024, 4 * kH, WTg2,  3072, 2048, 0);
  T(W_fc,    kV,     kH,   kV,     WTfc,  kH,   0, 0);
  zero_bf16<<<(32 * 1024 + 255) / 256, 256, 0, stream>>>(WTfc + (size_t)12000 * 1024, 32 * 1024);
  pack_biases<<<20, 256, 0, stream>>>(b_ih1, b_hh1, bx_gate, bh_gate, b_ih2, b_hh2,
                                      bias_g1, bias_g2);
  gather_emb<<<(kB * kT * kE + 255) / 256, 256, 0, stream>>>(caps, emb, wembb);

  // Vfeat = relu(images @ W_img + b_img)   [4608 x 1024]
  {
    GemmBArgs ga = {};
    ga.seg[0] = {imagesb, kRaw, 0, kRaw};
    ga.nseg = 1; ga.WT = WTimg; ga.ldk = kRaw; ga.bias = b_img;
    ga.C = Vfeat; ga.ldc = kH; ga.N = kH; ga.Ktot = kRaw; ga.act = 1;
    gemm_bf16<<<dim3(kH / 64, kB * kP / 64), 256, 0, stream>>>(ga);
  }
  mean_p<<<(kB * kH + 255) / 256, 256, 0, stream>>>(Vfeat, meanV);
  {  // glob (fp32, dual-write bf16)
    GemmArgs ga = {};
    ga.seg[0] = {meanV, W_glob, kH, kH, kE};
    ga.nseg = 1; ga.bias0 = b_glob;
    ga.C = glob; ga.C16 = globb; ga.ldc = kE; ga.M = kB; ga.N = kE; ga.act = 1;
    gemm_ms<<<dim3((kE + kBN - 1) / kBN, (kB + kBM - 1) / kBM), 256, 0, stream>>>(ga);
  }
  {  // img_proj (fp32)
    GemmArgs ga = {};
    ga.seg[0] = {Vfeat, Wv, kH, kH, kP};
    ga.nseg = 1; ga.bias0 = bv;
    ga.C = img_proj; ga.ldc = kP; ga.M = kB * kP; ga.N = kP; ga.act = 0;
    gemm_ms<<<dim3(1, (kB * kP + kBM - 1) / kBM), 256, 0, stream>>>(ga);
  }

  // ---- 20 decode steps
  for (int t = 0; t < kT; ++t) {
    {  // g1 + sentinel: [128 x 5120], K = 3072
      GemmBArgs ga = {};
      ga.seg[0] = {h2b, kH, 0, kH};
      ga.seg[1] = {globb, kE, kH, kH + kE};
      ga.seg[2] = {wembb + (size_t)t * kE, kT * kE, kH + kE, 2048};
      ga.seg[3] = {h1b, kH, 2048, 3072};
      ga.nseg = 4; ga.WT = WTg1; ga.ldk = 3072; ga.bias = bias_g1;
      ga.C = g1out; ga.ldc = 5120; ga.N = 5120; ga.Ktot = 3072; ga.act = 0;
      gemm_bf16<<<dim3(5120 / 64, kB / 64), 256, 0, stream>>>(ga);
    }
    lstm1_elem<<<(kB * kH + 255) / 256, 256, 0, stream>>>(g1out, c1, h1, h1b, st);
    attn_step<<<kB, 256, 0, stream>>>(h1, st, img_proj, Vfeat, Wg, Ws_, bs_, wh,
                                      chat, chatb, out_alphas, out_betas, t);
    {  // g2: [128 x 4096], K = 3072
      GemmBArgs ga = {};
      ga.seg[0] = {chatb, kH, 0, kH};
      ga.seg[1] = {h1b, kH, kH, 2048};
      ga.seg[2] = {h2b, kH, 2048, 3072};
      ga.nseg = 3; ga.WT = WTg2; ga.ldk = 3072; ga.bias = bias_g2;
      ga.C = g1out; ga.ldc = 4096; ga.N = 4096; ga.Ktot = 3072; ga.act = 0;
      gemm_bf16<<<dim3(4096 / 64, kB / 64), 256, 0, stream>>>(ga);
    }
    lstm2_elem<<<(kB * kH + 255) / 256, 256, 0, stream>>>(g1out, c2, h2, h2b, chat, sbufb);
    {  // fc: [128 x 12000], K = 1024
      GemmBArgs ga = {};
      ga.seg[0] = {sbufb, kH, 0, kH};
      ga.nseg = 1; ga.WT = WTfc; ga.ldk = kH; ga.bias = b_fc;
      ga.C = out + (size_t)t * kV; ga.ldc = kT * kV; ga.N = kV; ga.Ktot = kH; ga.act = 0;
      gemm_bf16<<<dim3(12032 / 64, kB / 64), 256, 0, stream>>>(ga);
    }
  }
}

// Round 3
// 2418.676 us; speedup vs baseline: 10.2303x; 1.3480x over previous
//
#include <hip/hip_runtime.h>
#include <hip/hip_bf16.h>
#include <math.h>

typedef __attribute__((ext_vector_type(4))) float f32x4;
typedef __attribute__((ext_vector_type(8))) short bf16x8;

constexpr int kB = 128, kT = 20, kH = 1024, kE = 512, kP = 36, kRaw = 2048, kV = 12000;

__device__ __forceinline__ float sigf(float x) { return 1.0f / (1.0f + expf(-x)); }

#define AS1C const __attribute__((address_space(1))) void*
#define AS3P __attribute__((address_space(3))) void*

// ---------------------------------------------------------------- utilities
__global__ __launch_bounds__(256) void zero_f32(float* p, int n) {
  int i = blockIdx.x * 256 + threadIdx.x;
  if (i < n) p[i] = 0.0f;
}
__global__ __launch_bounds__(256) void zero_bf16(__hip_bfloat16* p, int n) {
  int i = blockIdx.x * 256 + threadIdx.x;
  if (i < n) p[i] = __float2bfloat16(0.0f);
}
__global__ __launch_bounds__(256) void f32_to_bf16(const float* __restrict__ src,
                                                   __hip_bfloat16* __restrict__ dst, int n4) {
  int i = blockIdx.x * 256 + threadIdx.x;
  if (i >= n4) return;
  float4 v = reinterpret_cast<const float4*>(src)[i];
  __hip_bfloat16* d = dst + (size_t)i * 4;
  d[0] = __float2bfloat16(v.x); d[1] = __float2bfloat16(v.y);
  d[2] = __float2bfloat16(v.z); d[3] = __float2bfloat16(v.w);
}

// dst[n + n_off][k + k_off] = bf16(src[k][n]);  src is [Kblk][ld_src]
__global__ __launch_bounds__(256) void transpose_to_bf16(const float* __restrict__ src, int ld_src,
                                                         int Kblk, int Nblk,
                                                         __hip_bfloat16* __restrict__ dst, int lddst,
                                                         int k_off, int n_off) {
  __shared__ float t[32][33];
  int n0 = blockIdx.x * 32, k0 = blockIdx.y * 32;
  int tx = threadIdx.x & 31, ty = threadIdx.x >> 5;  // 32 x 8
  #pragma unroll
  for (int i = 0; i < 32; i += 8) {
    int k = k0 + ty + i, n = n0 + tx;
    t[ty + i][tx] = (k < Kblk && n < Nblk) ? src[(size_t)k * ld_src + n] : 0.0f;
  }
  __syncthreads();
  #pragma unroll
  for (int i = 0; i < 32; i += 8) {
    int n = n0 + ty + i, k = k0 + tx;
    if (n < Nblk && k < Kblk)
      dst[(size_t)(n + n_off) * lddst + k + k_off] = __float2bfloat16(t[tx][ty + i]);
  }
}

__global__ __launch_bounds__(256) void pack_biases(const float* b_ih1, const float* b_hh1,
                                                   const float* bx, const float* bh,
                                                   const float* b_ih2, const float* b_hh2,
                                                   float* bias_g1, float* bias_g2) {
  int i = blockIdx.x * 256 + threadIdx.x;
  if (i < 4096) {
    bias_g1[i] = b_ih1[i] + b_hh1[i];
    bias_g2[i] = b_ih2[i] + b_hh2[i];
  } else if (i < 5120) {
    bias_g1[i] = bx[i - 4096] + bh[i - 4096];
  }
}

// ------------------------------------------------------- bf16 MFMA GEMM
// C[M,N] = act( concat_K(A_segs) @ WT^T + bias ), WT is [N][K] bf16.
// BM=BN=64, BK=128, double-buffered LDS (T3-minimum 2-phase pipeline).
// M, Ktot, seg boundaries multiples of 128 (M mult of 64); N bound-checked on
// write only (WT padded to mult-64 rows).
struct SegB { const __hip_bfloat16* A; int lda; int kstart; int kend; };
struct GemmBArgs {
  SegB seg[4]; int nseg;
  const __hip_bfloat16* WT; int ldk;
  const float* bias;
  float* C; __hip_bfloat16* C16; int ldc; int N; int Ktot; int act;
};

__global__ __launch_bounds__(256) void gemm_bf16(GemmBArgs ga) {
  __shared__ char lds[65536];  // [buf][A 16K | B 16K]
  const int bm = blockIdx.y * 64;
  const int bn = blockIdx.x * 64;
  const int tid = threadIdx.x;
  const int lane = tid & 63;
  const int w = tid >> 6;
  const int wr = w >> 1, wc = w & 1;

  // staging geometry: 4 rounds per 16 KB matrix tile; linear LDS dest,
  // inverse-swizzled global source (XOR involution, T2/G4).
  int rowS[4], scbS[4], dstS[4];
  #pragma unroll
  for (int j = 0; j < 4; ++j) {
    int off = ((j * 4 + w) * 64 + lane) * 16;   // linear byte in 16 KB tile
    int row = off >> 8, colb = off & 255;       // row stride 256 B (BK=128 bf16)
    rowS[j] = row;
    scbS[j] = colb ^ ((row & 7) << 4);
    dstS[j] = (j * 4 + w) * 1024;               // wave-uniform LDS base
  }

  f32x4 acc[2][2] = {};
  const int nit = ga.Ktot >> 7;

  auto stage = [&](int it, int buf) {
    const int k0 = it << 7;
    int si = 0;
    while (k0 >= ga.seg[si].kend) ++si;
    const __hip_bfloat16* Aseg = ga.seg[si].A;
    const int lda = ga.seg[si].lda;
    const int ks = k0 - ga.seg[si].kstart;
    char* baseA = lds + buf * 32768;
    char* baseB = baseA + 16384;
    #pragma unroll
    for (int j = 0; j < 4; ++j) {
      const __hip_bfloat16* sA = Aseg + (size_t)(bm + rowS[j]) * lda + ks + (scbS[j] >> 1);
      __builtin_amdgcn_global_load_lds((AS1C)sA, (AS3P)(baseA + dstS[j]), 16, 0, 0);
      const __hip_bfloat16* sB = ga.WT + (size_t)(bn + rowS[j]) * ga.ldk + k0 + (scbS[j] >> 1);
      __builtin_amdgcn_global_load_lds((AS1C)sB, (AS3P)(baseB + dstS[j]), 16, 0, 0);
    }
  };

  auto compute = [&](int buf) {
    const char* baseA = lds + buf * 32768;
    const char* baseB = baseA + 16384;
    #pragma unroll
    for (int kk = 0; kk < 4; ++kk) {
      bf16x8 a[2], b[2];
      #pragma unroll
      for (int f = 0; f < 2; ++f) {
        int row = wr * 32 + f * 16 + (lane & 15);
        int cb = kk * 64 + (lane >> 4) * 16;
        a[f] = *(const bf16x8*)(baseA + row * 256 + (cb ^ ((row & 7) << 4)));
        int nl = wc * 32 + f * 16 + (lane & 15);
        b[f] = *(const bf16x8*)(baseB + nl * 256 + (cb ^ ((nl & 7) << 4)));
      }
      #pragma unroll
      for (int fm = 0; fm < 2; ++fm)
        #pragma unroll
        for (int fn = 0; fn < 2; ++fn)
          acc[fm][fn] = __builtin_amdgcn_mfma_f32_16x16x32_bf16(a[fm], b[fn], acc[fm][fn], 0, 0, 0);
    }
  };

  // prologue
  stage(0, 0);
  asm volatile("s_waitcnt vmcnt(0)" ::: "memory");
  __builtin_amdgcn_s_barrier();
  // main loop: issue next-tile loads, compute current, then drain + barrier
  for (int it = 0; it < nit - 1; ++it) {
    stage(it + 1, (it & 1) ^ 1);
    compute(it & 1);
    asm volatile("s_waitcnt vmcnt(0)" ::: "memory");
    __builtin_amdgcn_s_barrier();
  }
  compute((nit - 1) & 1);

  #pragma unroll
  for (int fm = 0; fm < 2; ++fm) {
    int rbase = bm + wr * 32 + fm * 16 + (lane >> 4) * 4;
    #pragma unroll
    for (int fn = 0; fn < 2; ++fn) {
      int col = bn + wc * 32 + fn * 16 + (lane & 15);
      if (col >= ga.N) continue;
      float bv = ga.bias ? ga.bias[col] : 0.0f;
      #pragma unroll
      for (int j = 0; j < 4; ++j) {
        float v = acc[fm][fn][j] + bv;
        if (ga.act == 1) v = fmaxf(v, 0.0f);
        size_t off = (size_t)(rbase + j) * ga.ldc + col;
        if (ga.C) ga.C[off] = v;
        if (ga.C16) ga.C16[off] = __float2bfloat16(v);
      }
    }
  }
}

// ------------------------------------------------------- small fused kernels
__global__ __launch_bounds__(256) void mean_p(const float* __restrict__ Vfeat,
                                              __hip_bfloat16* __restrict__ meanVb) {
  int idx = blockIdx.x * 256 + threadIdx.x;
  if (idx >= kB * kH) return;
  int b = idx >> 10, h = idx & 1023;
  float sm = 0.0f;
  for (int p = 0; p < kP; ++p) sm += Vfeat[((size_t)b * kP + p) * kH + h];
  meanVb[idx] = __float2bfloat16(sm * (1.0f / kP));
}

__global__ __launch_bounds__(256) void gather_emb(const int* __restrict__ caps,
                                                  const float* __restrict__ emb,
                                                  __hip_bfloat16* __restrict__ wembb) {
  int idx = blockIdx.x * 256 + threadIdx.x;
  if (idx >= kB * kT * kE) return;
  int e = idx % kE;
  int bt = idx / kE;
  int t = bt % kT;
  int b = bt / kT;
  int tok = caps[b * (kT + 1) + t];
  wembb[idx] = __float2bfloat16(emb[(size_t)tok * kE + e]);
}

// LSTM1 gates + sentinel + full adaptive-attention step. One block per batch
// element; h1/st live only in LDS. g layout: [b][5120].
__global__ __launch_bounds__(256) void step1_fused(
    const float* __restrict__ g, float* __restrict__ c1,
    __hip_bfloat16* __restrict__ h1b,
    const float* __restrict__ img_proj, const float* __restrict__ Vfeat,
    const float* __restrict__ Wg, const float* __restrict__ Ws,
    const float* __restrict__ bs, const float* __restrict__ wh,
    float* __restrict__ c_hat, __hip_bfloat16* __restrict__ c_hatb,
    float* __restrict__ out_alphas, float* __restrict__ out_betas, int t) {
  const int b = blockIdx.x;
  const int tid = threadIdx.x;
  __shared__ float sh_h1[kH];
  __shared__ float sh_st[kH];
  __shared__ float htp[kP];
  __shared__ float stp[kP];
  __shared__ float zz[kP];
  __shared__ float alpha[kP];
  __shared__ float sred[2];

  const float* gr = g + (size_t)b * 5120;
  #pragma unroll
  for (int i = 0; i < 4; ++i) {
    int h = tid + i * 256;
    float ig = sigf(gr[h]);
    float fg = sigf(gr[kH + h]);
    float gg = tanhf(gr[2 * kH + h]);
    float og = sigf(gr[3 * kH + h]);
    int idx = b * kH + h;
    float c = fg * c1[idx] + ig * gg;
    float tc = tanhf(c);
    float hn = og * tc;
    c1[idx] = c;
    h1b[idx] = __float2bfloat16(hn);
    sh_h1[h] = hn;
    sh_st[h] = sigf(gr[4 * kH + h]) * tc;
  }
  __syncthreads();

  if (tid < kP) {
    float acc = 0.0f;
    for (int h = 0; h < kH; ++h) acc = fmaf(sh_h1[h], Wg[h * kP + tid], acc);
    htp[tid] = acc;
  } else if (tid >= 64 && tid < 64 + kP) {
    int j = tid - 64;
    float acc = 0.0f;
    for (int h = 0; h < kH; ++h) acc = fmaf(sh_st[h], Ws[h * kP + j], acc);
    stp[j] = acc;
  }
  __syncthreads();
  if (tid < kP) {
    const float* ip = img_proj + ((size_t)b * kP + tid) * kP;
    float acc = 0.0f;
    for (int j = 0; j < kP; ++j) acc = fmaf(tanhf(ip[j] + htp[j]), wh[j], acc);
    zz[tid] = acc;
  } else if (tid == 64) {
    float acc = 0.0f;
    for (int j = 0; j < kP; ++j) acc = fmaf(tanhf(stp[j] + bs[j] + htp[j]), wh[j], acc);
    sred[0] = acc;  // att_vs
  }
  __syncthreads();
  if (tid == 0) {
    float m = -1e30f;
    for (int p = 0; p < kP; ++p) m = fmaxf(m, zz[p]);
    float se = 0.0f;
    for (int p = 0; p < kP; ++p) { float e = expf(zz[p] - m); alpha[p] = e; se += e; }
    float inv = 1.0f / se;
    for (int p = 0; p < kP; ++p) alpha[p] *= inv;
    float av = sred[0];
    float m2 = fmaxf(m, av);
    float eb = expf(av - m2);
    float beta = eb / (se * expf(m - m2) + eb);
    sred[1] = beta;
    out_betas[b * kT + t] = beta;
  }
  __syncthreads();
  if (tid < kP) out_alphas[((size_t)b * kT + t) * kP + tid] = alpha[tid];
  const float beta = sred[1];
  #pragma unroll
  for (int i = 0; i < 4; ++i) {
    int h = tid + i * 256;
    float ctx = 0.0f;
    for (int p = 0; p < kP; ++p) ctx = fmaf(alpha[p], Vfeat[((size_t)b * kP + p) * kH + h], ctx);
    float v = beta * sh_st[h] + (1.0f - beta) * ctx;
    c_hat[(size_t)b * kH + h] = v;
    c_hatb[(size_t)b * kH + h] = __float2bfloat16(v);
  }
}

// g layout: [b][4096]
__global__ __launch_bounds__(256) void lstm2_elem(const float* __restrict__ g,
                                                  float* __restrict__ c2,
                                                  __hip_bfloat16* __restrict__ h2b,
                                                  const float* __restrict__ c_hat,
                                                  __hip_bfloat16* __restrict__ sbufb) {
  int idx = blockIdx.x * 256 + threadIdx.x;
  if (idx >= kB * kH) return;
  int b = idx >> 10, h = idx & 1023;
  const float* gr = g + (size_t)b * 4 * kH;
  float ig = sigf(gr[h]);
  float fg = sigf(gr[kH + h]);
  float gg = tanhf(gr[2 * kH + h]);
  float og = sigf(gr[3 * kH + h]);
  float c = fg * c2[idx] + ig * gg;
  float hn = og * tanhf(c);
  c2[idx] = c;
  h2b[idx] = __float2bfloat16(hn);
  sbufb[idx] = __float2bfloat16(c_hat[idx] + hn);
}

// ------------------------------------------------------------------ launch
extern "C" void kernel_launch(void* const* d_in, const int* in_sizes, int n_in,
                              void* d_out, int out_size, void* d_ws, size_t ws_size,
                              hipStream_t stream) {
  const float* images  = (const float*)d_in[0];
  const int*   caps    = (const int*)d_in[1];
  const float* W_img   = (const float*)d_in[3];
  const float* b_img   = (const float*)d_in[4];
  const float* W_glob  = (const float*)d_in[5];
  const float* b_glob  = (const float*)d_in[6];
  const float* W_ih1   = (const float*)d_in[7];
  const float* W_hh1   = (const float*)d_in[8];
  const float* b_ih1   = (const float*)d_in[9];
  const float* b_hh1   = (const float*)d_in[10];
  const float* Wx_gate = (const float*)d_in[11];
  const float* bx_gate = (const float*)d_in[12];
  const float* Wh_gate = (const float*)d_in[13];
  const float* bh_gate = (const float*)d_in[14];
  const float* W_ih2   = (const float*)d_in[15];
  const float* W_hh2   = (const float*)d_in[16];
  const float* b_ih2   = (const float*)d_in[17];
  const float* b_hh2   = (const float*)d_in[18];
  const float* Wv      = (const float*)d_in[19];
  const float* bv      = (const float*)d_in[20];
  const float* Ws_     = (const float*)d_in[21];
  const float* bs_     = (const float*)d_in[22];
  const float* Wg      = (const float*)d_in[23];
  const float* wh      = (const float*)d_in[24];
  const float* emb     = (const float*)d_in[25];
  const float* W_fc    = (const float*)d_in[26];
  const float* b_fc    = (const float*)d_in[27];

  float* out = (float*)d_out;
  float* out_alphas = out + (size_t)kB * kT * kV;
  float* out_betas  = out_alphas + (size_t)kB * kT * kP;

  char* base = (char*)d_ws;
  auto alloc = [&](size_t bytes) {
    char* p = base;
    base += (bytes + 255) & ~(size_t)255;
    return p;
  };
  float*          Vfeat   = (float*)alloc((size_t)kB * kP * kH * 4);
  __hip_bfloat16* Vfeatb  = (__hip_bfloat16*)alloc((size_t)kB * kP * kH * 2);
  __hip_bfloat16* imagesb = (__hip_bfloat16*)alloc((size_t)kB * kP * kRaw * 2);
  __hip_bfloat16* WTg1    = (__hip_bfloat16*)alloc((size_t)5120 * 3072 * 2);
  __hip_bfloat16* WTg2    = (__hip_bfloat16*)alloc((size_t)4096 * 3072 * 2);
  __hip_bfloat16* WTfc    = (__hip_bfloat16*)alloc((size_t)12032 * 1024 * 2);
  __hip_bfloat16* WTimg   = (__hip_bfloat16*)alloc((size_t)1024 * 2048 * 2);
  __hip_bfloat16* WTglob  = (__hip_bfloat16*)alloc((size_t)512 * 1024 * 2);
  __hip_bfloat16* WTv     = (__hip_bfloat16*)alloc((size_t)64 * 1024 * 2);
  __hip_bfloat16* wembb   = (__hip_bfloat16*)alloc((size_t)kB * kT * kE * 2);
  float*          img_proj= (float*)alloc((size_t)kB * kP * kP * 4);
  __hip_bfloat16* globb   = (__hip_bfloat16*)alloc((size_t)kB * kE * 2);
  __hip_bfloat16* meanVb  = (__hip_bfloat16*)alloc((size_t)kB * kH * 2);
  float*          c1      = (float*)alloc((size_t)2 * kB * kH * 4);  // c1, c2
  float*          c2      = c1 + kB * kH;
  __hip_bfloat16* h1b     = (__hip_bfloat16*)alloc((size_t)2 * kB * kH * 2);
  __hip_bfloat16* h2b     = h1b + kB * kH;
  float*          g1out   = (float*)alloc((size_t)kB * 5120 * 4);
  float*          chat    = (float*)alloc((size_t)kB * kH * 4);
  __hip_bfloat16* chatb   = (__hip_bfloat16*)alloc((size_t)kB * kH * 2);
  __hip_bfloat16* sbufb   = (__hip_bfloat16*)alloc((size_t)kB * kH * 2);
  float*          bias_g1 = (float*)alloc(5120 * 4);
  float*          bias_g2 = (float*)alloc(4096 * 4);

  // ---- once-per-call prep
  zero_f32<<<(2 * kB * kH + 255) / 256, 256, 0, stream>>>(c1, 2 * kB * kH);
  zero_bf16<<<(2 * kB * kH + 255) / 256, 256, 0, stream>>>(h1b, 2 * kB * kH);
  {
    int n4 = kB * kP * kRaw / 4;
    f32_to_bf16<<<(n4 + 255) / 256, 256, 0, stream>>>(images, imagesb, n4);
  }
  auto T = [&](const float* src, int ldsrc, int K, int N, __hip_bfloat16* dst, int lddst,
               int koff, int noff) {
    transpose_to_bf16<<<dim3((N + 31) / 32, (K + 31) / 32), 256, 0, stream>>>(
        src, ldsrc, K, N, dst, lddst, koff, noff);
  };
  T(W_img,   kH,     kRaw, kH,     WTimg,  kRaw, 0, 0);
  T(W_glob,  kE,     kH,   kE,     WTglob, kH,   0, 0);
  zero_bf16<<<(64 * 1024 + 255) / 256, 256, 0, stream>>>(WTv, 64 * 1024);
  T(Wv,      kP,     kH,   kP,     WTv,    kH,   0, 0);
  T(W_ih1,   4 * kH, 2048, 4 * kH, WTg1,   3072, 0, 0);
  T(W_hh1,   4 * kH, 1024, 4 * kH, WTg1,   3072, 2048, 0);
  T(Wx_gate, kH,     2048, kH,     WTg1,   3072, 0, 4096);
  T(Wh_gate, kH,     1024, kH,     WTg1,   3072, 2048, 4096);
  T(W_ih2,   4 * kH, 2048, 4 * kH, WTg2,   3072, 0, 0);
  T(W_hh2,   4 * kH, 1024, 4 * kH, WTg2,   3072, 2048, 0);
  T(W_fc,    kV,     kH,   kV,     WTfc,   kH,   0, 0);
  zero_bf16<<<(32 * 1024 + 255) / 256, 256, 0, stream>>>(WTfc + (size_t)12000 * 1024, 32 * 1024);
  pack_biases<<<20, 256, 0, stream>>>(b_ih1, b_hh1, bx_gate, bh_gate, b_ih2, b_hh2,
                                      bias_g1, bias_g2);
  gather_emb<<<(kB * kT * kE + 255) / 256, 256, 0, stream>>>(caps, emb, wembb);

  // Vfeat = relu(images @ W_img + b_img)   [4608 x 1024], K=2048
  {
    GemmBArgs ga = {};
    ga.seg[0] = {imagesb, kRaw, 0, kRaw};
    ga.nseg = 1; ga.WT = WTimg; ga.ldk = kRaw; ga.bias = b_img;
    ga.C = Vfeat; ga.C16 = Vfeatb; ga.ldc = kH; ga.N = kH; ga.Ktot = kRaw; ga.act = 1;
    gemm_bf16<<<dim3(kH / 64, kB * kP / 64), 256, 0, stream>>>(ga);
  }
  mean_p<<<(kB * kH + 255) / 256, 256, 0, stream>>>(Vfeat, meanVb);
  // glob = relu(meanV @ W_glob + b_glob)   [128 x 512], K=1024 (bf16 out only)
  {
    GemmBArgs ga = {};
    ga.seg[0] = {meanVb, kH, 0, kH};
    ga.nseg = 1; ga.WT = WTglob; ga.ldk = kH; ga.bias = b_glob;
    ga.C = nullptr; ga.C16 = globb; ga.ldc = kE; ga.N = kE; ga.Ktot = kH; ga.act = 1;
    gemm_bf16<<<dim3(kE / 64, kB / 64), 256, 0, stream>>>(ga);
  }
  // img_proj = Vfeat @ Wv + bv   [4608 x 36], K=1024
  {
    GemmBArgs ga = {};
    ga.seg[0] = {Vfeatb, kH, 0, kH};
    ga.nseg = 1; ga.WT = WTv; ga.ldk = kH; ga.bias = bv;
    ga.C = img_proj; ga.C16 = nullptr; ga.ldc = kP; ga.N = kP; ga.Ktot = kH; ga.act = 0;
    gemm_bf16<<<dim3(1, kB * kP / 64), 256, 0, stream>>>(ga);
  }

  // ---- 20 decode steps
  for (int t = 0; t < kT; ++t) {
    {  // g1 + sentinel: [128 x 5120], K = 3072
      GemmBArgs ga = {};
      ga.seg[0] = {h2b, kH, 0, kH};
      ga.seg[1] = {globb, kE, kH, kH + kE};
      ga.seg[2] = {wembb + (size_t)t * kE, kT * kE, kH + kE, 2048};
      ga.seg[3] = {h1b, kH, 2048, 3072};
      ga.nseg = 4; ga.WT = WTg1; ga.ldk = 3072; ga.bias = bias_g1;
      ga.C = g1out; ga.C16 = nullptr; ga.ldc = 5120; ga.N = 5120; ga.Ktot = 3072; ga.act = 0;
      gemm_bf16<<<dim3(5120 / 64, kB / 64), 256, 0, stream>>>(ga);
    }
    step1_fused<<<kB, 256, 0, stream>>>(g1out, c1, h1b, img_proj, Vfeat,
                                        Wg, Ws_, bs_, wh, chat, chatb,
                                        out_alphas, out_betas, t);
    {  // g2: [128 x 4096], K = 3072
      GemmBArgs ga = {};
      ga.seg[0] = {chatb, kH, 0, kH};
      ga.seg[1] = {h1b, kH, kH, 2048};
      ga.seg[2] = {h2b, kH, 2048, 3072};
      ga.nseg = 3; ga.WT = WTg2; ga.ldk = 3072; ga.bias = bias_g2;
      ga.C = g1out; ga.C16 = nullptr; ga.ldc = 4096; ga.N = 4096; ga.Ktot = 3072; ga.act = 0;
      gemm_bf16<<<dim3(4096 / 64, kB / 64), 256, 0, stream>>>(ga);
    }
    lstm2_elem<<<(kB * kH + 255) / 256, 256, 0, stream>>>(g1out, c2, h2b, chat, sbufb);
    {  // fc: [128 x 12000], K = 1024
      GemmBArgs ga = {};
      ga.seg[0] = {sbufb, kH, 0, kH};
      ga.nseg = 1; ga.WT = WTfc; ga.ldk = kH; ga.bias = b_fc;
      ga.C = out + (size_t)t * kV; ga.C16 = nullptr; ga.ldc = kT * kV; ga.N = kV; ga.Ktot = kH; ga.act = 0;
      gemm_bf16<<<dim3(12032 / 64, kB / 64), 256, 0, stream>>>(ga);
    }
  }
}

// Round 4
// 2062.818 us; speedup vs baseline: 11.9952x; 1.1725x over previous
//
#include <hip/hip_runtime.h>
#include <hip/hip_bf16.h>
#include <math.h>

typedef __attribute__((ext_vector_type(4))) float f32x4;
typedef __attribute__((ext_vector_type(8))) short bf16x8;

constexpr int kB = 128, kT = 20, kH = 1024, kE = 512, kP = 36, kRaw = 2048, kV = 12000;

__device__ __forceinline__ float sigf(float x) { return 1.0f / (1.0f + expf(-x)); }

#define AS1C const __attribute__((address_space(1))) void*
#define AS3P __attribute__((address_space(3))) void*

// ---------------------------------------------------------------- utilities
__global__ __launch_bounds__(256) void zero_f32(float* p, int n) {
  int i = blockIdx.x * 256 + threadIdx.x;
  if (i < n) p[i] = 0.0f;
}
__global__ __launch_bounds__(256) void zero_bf16(__hip_bfloat16* p, int n) {
  int i = blockIdx.x * 256 + threadIdx.x;
  if (i < n) p[i] = __float2bfloat16(0.0f);
}
__global__ __launch_bounds__(256) void f32_to_bf16(const float* __restrict__ src,
                                                   __hip_bfloat16* __restrict__ dst, int n4) {
  int i = blockIdx.x * 256 + threadIdx.x;
  if (i >= n4) return;
  float4 v = reinterpret_cast<const float4*>(src)[i];
  __hip_bfloat16* d = dst + (size_t)i * 4;
  d[0] = __float2bfloat16(v.x); d[1] = __float2bfloat16(v.y);
  d[2] = __float2bfloat16(v.z); d[3] = __float2bfloat16(v.w);
}

// dst[n + n_off][k + k_off] = bf16(src[k][n]);  src is [Kblk][ld_src]
__global__ __launch_bounds__(256) void transpose_to_bf16(const float* __restrict__ src, int ld_src,
                                                         int Kblk, int Nblk,
                                                         __hip_bfloat16* __restrict__ dst, int lddst,
                                                         int k_off, int n_off) {
  __shared__ float t[32][33];
  int n0 = blockIdx.x * 32, k0 = blockIdx.y * 32;
  int tx = threadIdx.x & 31, ty = threadIdx.x >> 5;  // 32 x 8
  #pragma unroll
  for (int i = 0; i < 32; i += 8) {
    int k = k0 + ty + i, n = n0 + tx;
    t[ty + i][tx] = (k < Kblk && n < Nblk) ? src[(size_t)k * ld_src + n] : 0.0f;
  }
  __syncthreads();
  #pragma unroll
  for (int i = 0; i < 32; i += 8) {
    int n = n0 + ty + i, k = k0 + tx;
    if (n < Nblk && k < Kblk)
      dst[(size_t)(n + n_off) * lddst + k + k_off] = __float2bfloat16(t[tx][ty + i]);
  }
}

__global__ __launch_bounds__(256) void pack_biases(const float* b_ih1, const float* b_hh1,
                                                   const float* bx, const float* bh,
                                                   const float* b_ih2, const float* b_hh2,
                                                   float* bias_g1, float* bias_g2) {
  int i = blockIdx.x * 256 + threadIdx.x;
  if (i < 4096) {
    bias_g1[i] = b_ih1[i] + b_hh1[i];
    bias_g2[i] = b_ih2[i] + b_hh2[i];
  } else if (i < 5120) {
    bias_g1[i] = bx[i - 4096] + bh[i - 4096];
  }
}

// ------------------------------------------------------- bf16 MFMA GEMM
// C[M,N] = act( concat_K(A_segs) @ WT^T + bias ), WT is [N][K] bf16.
// BM=BN=64, BK=128, double-buffered LDS (T3-minimum 2-phase pipeline).
struct SegB { const __hip_bfloat16* A; int lda; int kstart; int kend; };
struct GemmBArgs {
  SegB seg[4]; int nseg;
  const __hip_bfloat16* WT; int ldk;
  const float* bias;
  float* C; __hip_bfloat16* C16; int ldc; int N; int Ktot; int act;
};

__global__ __launch_bounds__(256) void gemm_bf16(GemmBArgs ga) {
  __shared__ char lds[65536];  // [buf][A 16K | B 16K]
  const int bm = blockIdx.y * 64;
  const int bn = blockIdx.x * 64;
  const int tid = threadIdx.x;
  const int lane = tid & 63;
  const int w = tid >> 6;
  const int wr = w >> 1, wc = w & 1;

  int rowS[4], scbS[4], dstS[4];
  #pragma unroll
  for (int j = 0; j < 4; ++j) {
    int off = ((j * 4 + w) * 64 + lane) * 16;   // linear byte in 16 KB tile
    int row = off >> 8, colb = off & 255;       // row stride 256 B (BK=128 bf16)
    rowS[j] = row;
    scbS[j] = colb ^ ((row & 7) << 4);
    dstS[j] = (j * 4 + w) * 1024;               // wave-uniform LDS base
  }

  f32x4 acc[2][2] = {};
  const int nit = ga.Ktot >> 7;

  auto stage = [&](int it, int buf) {
    const int k0 = it << 7;
    int si = 0;
    while (k0 >= ga.seg[si].kend) ++si;
    const __hip_bfloat16* Aseg = ga.seg[si].A;
    const int lda = ga.seg[si].lda;
    const int ks = k0 - ga.seg[si].kstart;
    char* baseA = lds + buf * 32768;
    char* baseB = baseA + 16384;
    #pragma unroll
    for (int j = 0; j < 4; ++j) {
      const __hip_bfloat16* sA = Aseg + (size_t)(bm + rowS[j]) * lda + ks + (scbS[j] >> 1);
      __builtin_amdgcn_global_load_lds((AS1C)sA, (AS3P)(baseA + dstS[j]), 16, 0, 0);
      const __hip_bfloat16* sB = ga.WT + (size_t)(bn + rowS[j]) * ga.ldk + k0 + (scbS[j] >> 1);
      __builtin_amdgcn_global_load_lds((AS1C)sB, (AS3P)(baseB + dstS[j]), 16, 0, 0);
    }
  };

  auto compute = [&](int buf) {
    const char* baseA = lds + buf * 32768;
    const char* baseB = baseA + 16384;
    #pragma unroll
    for (int kk = 0; kk < 4; ++kk) {
      bf16x8 a[2], b[2];
      #pragma unroll
      for (int f = 0; f < 2; ++f) {
        int row = wr * 32 + f * 16 + (lane & 15);
        int cb = kk * 64 + (lane >> 4) * 16;
        a[f] = *(const bf16x8*)(baseA + row * 256 + (cb ^ ((row & 7) << 4)));
        int nl = wc * 32 + f * 16 + (lane & 15);
        b[f] = *(const bf16x8*)(baseB + nl * 256 + (cb ^ ((nl & 7) << 4)));
      }
      #pragma unroll
      for (int fm = 0; fm < 2; ++fm)
        #pragma unroll
        for (int fn = 0; fn < 2; ++fn)
          acc[fm][fn] = __builtin_amdgcn_mfma_f32_16x16x32_bf16(a[fm], b[fn], acc[fm][fn], 0, 0, 0);
    }
  };

  stage(0, 0);
  asm volatile("s_waitcnt vmcnt(0)" ::: "memory");
  __builtin_amdgcn_s_barrier();
  for (int it = 0; it < nit - 1; ++it) {
    stage(it + 1, (it & 1) ^ 1);
    compute(it & 1);
    asm volatile("s_waitcnt vmcnt(0)" ::: "memory");
    __builtin_amdgcn_s_barrier();
  }
  compute((nit - 1) & 1);

  #pragma unroll
  for (int fm = 0; fm < 2; ++fm) {
    int rbase = bm + wr * 32 + fm * 16 + (lane >> 4) * 4;
    #pragma unroll
    for (int fn = 0; fn < 2; ++fn) {
      int col = bn + wc * 32 + fn * 16 + (lane & 15);
      if (col >= ga.N) continue;
      float bv = ga.bias ? ga.bias[col] : 0.0f;
      #pragma unroll
      for (int j = 0; j < 4; ++j) {
        float v = acc[fm][fn][j] + bv;
        if (ga.act == 1) v = fmaxf(v, 0.0f);
        size_t off = (size_t)(rbase + j) * ga.ldc + col;
        if (ga.C) ga.C[off] = v;
        if (ga.C16) ga.C16[off] = __float2bfloat16(v);
      }
    }
  }
}

// ------------------------------------------------------- small fused kernels
__global__ __launch_bounds__(256) void mean_p(const float* __restrict__ Vfeat,
                                              __hip_bfloat16* __restrict__ meanVb) {
  int idx = blockIdx.x * 256 + threadIdx.x;
  if (idx >= kB * kH) return;
  int b = idx >> 10, h = idx & 1023;
  float sm = 0.0f;
  for (int p = 0; p < kP; ++p) sm += Vfeat[((size_t)b * kP + p) * kH + h];
  meanVb[idx] = __float2bfloat16(sm * (1.0f / kP));
}

__global__ __launch_bounds__(256) void gather_emb(const int* __restrict__ caps,
                                                  const float* __restrict__ emb,
                                                  __hip_bfloat16* __restrict__ wembb) {
  int idx = blockIdx.x * 256 + threadIdx.x;
  if (idx >= kB * kT * kE) return;
  int e = idx % kE;
  int bt = idx / kE;
  int t = bt % kT;
  int b = bt / kT;
  int tok = caps[b * (kT + 1) + t];
  wembb[idx] = __float2bfloat16(emb[(size_t)tok * kE + e]);
}

// LSTM1 gates + sentinel + full adaptive-attention step. One block per batch
// element. htp/stp are computed thread-major (coalesced Wg/Ws rows, 36
// register accumulators) + wave shuffle reduce; softmax is wave-parallel.
__global__ __launch_bounds__(256) void step1_fused(
    const float* __restrict__ g, float* __restrict__ c1,
    __hip_bfloat16* __restrict__ h1b,
    const float* __restrict__ img_proj, const float* __restrict__ Vfeat,
    const float* __restrict__ Wg, const float* __restrict__ Ws,
    const float* __restrict__ bs, const float* __restrict__ wh,
    float* __restrict__ c_hat, __hip_bfloat16* __restrict__ c_hatb,
    float* __restrict__ out_alphas, float* __restrict__ out_betas, int t) {
  const int b = blockIdx.x;
  const int tid = threadIdx.x;
  const int lane = tid & 63;
  const int w = tid >> 6;
  __shared__ float sh_h1[kH];
  __shared__ float sh_st[kH];
  __shared__ float wsum[4][36];
  __shared__ float htp[36];
  __shared__ float stp[36];
  __shared__ float alpha[kP];
  __shared__ float sred[4];  // 0: att_vs, 1: beta, 2: zmax, 3: zsum

  // ---- LSTM1 gates + sentinel
  const float* gr = g + (size_t)b * 5120;
  #pragma unroll
  for (int i = 0; i < 4; ++i) {
    int h = tid + i * 256;
    float ig = sigf(gr[h]);
    float fg = sigf(gr[kH + h]);
    float gg = tanhf(gr[2 * kH + h]);
    float og = sigf(gr[3 * kH + h]);
    int idx = b * kH + h;
    float c = fg * c1[idx] + ig * gg;
    float tc = tanhf(c);
    float hn = og * tc;
    c1[idx] = c;
    h1b[idx] = __float2bfloat16(hn);
    sh_h1[h] = hn;
    sh_st[h] = sigf(gr[4 * kH + h]) * tc;
  }
  __syncthreads();

  // ---- htp = h1 . Wg (pass 1);  stp = st . Ws (pass 2)
  #pragma unroll
  for (int pass = 0; pass < 2; ++pass) {
    const float* vec = pass == 0 ? sh_h1 : sh_st;
    const float* W = pass == 0 ? Wg : Ws;
    float pg[36];
    #pragma unroll
    for (int j = 0; j < 36; ++j) pg[j] = 0.0f;
    #pragma unroll
    for (int i = 0; i < 4; ++i) {
      int hh = tid + i * 256;
      float hv = vec[hh];
      const float4* wrow = reinterpret_cast<const float4*>(W + (size_t)hh * 36);
      #pragma unroll
      for (int r = 0; r < 9; ++r) {
        float4 wv = wrow[r];
        pg[4 * r + 0] = fmaf(hv, wv.x, pg[4 * r + 0]);
        pg[4 * r + 1] = fmaf(hv, wv.y, pg[4 * r + 1]);
        pg[4 * r + 2] = fmaf(hv, wv.z, pg[4 * r + 2]);
        pg[4 * r + 3] = fmaf(hv, wv.w, pg[4 * r + 3]);
      }
    }
    #pragma unroll
    for (int j = 0; j < 36; ++j) {
      float v = pg[j];
      #pragma unroll
      for (int off = 32; off > 0; off >>= 1) v += __shfl_down(v, off, 64);
      if (lane == 0) wsum[w][j] = v;
    }
    __syncthreads();
    if (tid < 36) {
      float s = wsum[0][tid] + wsum[1][tid] + wsum[2][tid] + wsum[3][tid];
      if (pass == 0) htp[tid] = s; else stp[tid] = s;
    }
    __syncthreads();
  }

  // ---- z (wave 0) and att_vs (wave 1), wave-parallel softmax
  if (w == 0) {
    float zz_r = -3.0e38f;
    if (lane < kP) {
      const float* ip = img_proj + ((size_t)b * kP + lane) * kP;
      float acc = 0.0f;
      #pragma unroll
      for (int j = 0; j < kP; ++j) acc = fmaf(tanhf(ip[j] + htp[j]), wh[j], acc);
      zz_r = acc;
    }
    float m = zz_r;
    #pragma unroll
    for (int off = 32; off > 0; off >>= 1) m = fmaxf(m, __shfl_xor(m, off, 64));
    float e = (lane < kP) ? expf(zz_r - m) : 0.0f;
    float s = e;
    #pragma unroll
    for (int off = 32; off > 0; off >>= 1) s += __shfl_xor(s, off, 64);
    if (lane < kP) alpha[lane] = e / s;
    if (lane == 0) { sred[2] = m; sred[3] = s; }
  } else if (w == 1) {
    float tv = 0.0f;
    if (lane < kP) tv = tanhf(stp[lane] + bs[lane] + htp[lane]) * wh[lane];
    #pragma unroll
    for (int off = 32; off > 0; off >>= 1) tv += __shfl_xor(tv, off, 64);
    if (lane == 0) sred[0] = tv;
  }
  __syncthreads();
  if (tid == 0) {
    float av = sred[0], m = sred[2], s = sred[3];
    float m2 = fmaxf(m, av);
    float eb = expf(av - m2);
    float beta = eb / (s * expf(m - m2) + eb);
    sred[1] = beta;
    out_betas[b * kT + t] = beta;
  }
  __syncthreads();
  if (tid < kP) out_alphas[((size_t)b * kT + t) * kP + tid] = alpha[tid];
  const float beta = sred[1];
  #pragma unroll
  for (int i = 0; i < 4; ++i) {
    int h = tid + i * 256;
    float ctx = 0.0f;
    for (int p = 0; p < kP; ++p) ctx = fmaf(alpha[p], Vfeat[((size_t)b * kP + p) * kH + h], ctx);
    float v = beta * sh_st[h] + (1.0f - beta) * ctx;
    c_hat[(size_t)b * kH + h] = v;
    c_hatb[(size_t)b * kH + h] = __float2bfloat16(v);
  }
}

// g layout: [b][4096]
__global__ __launch_bounds__(256) void lstm2_elem(const float* __restrict__ g,
                                                  float* __restrict__ c2,
                                                  __hip_bfloat16* __restrict__ h2b,
                                                  const float* __restrict__ c_hat,
                                                  __hip_bfloat16* __restrict__ sbufb) {
  int idx = blockIdx.x * 256 + threadIdx.x;
  if (idx >= kB * kH) return;
  int b = idx >> 10, h = idx & 1023;
  const float* gr = g + (size_t)b * 4 * kH;
  float ig = sigf(gr[h]);
  float fg = sigf(gr[kH + h]);
  float gg = tanhf(gr[2 * kH + h]);
  float og = sigf(gr[3 * kH + h]);
  float c = fg * c2[idx] + ig * gg;
  float hn = og * tanhf(c);
  c2[idx] = c;
  h2b[idx] = __float2bfloat16(hn);
  sbufb[idx] = __float2bfloat16(c_hat[idx] + hn);
}

// ------------------------------------------------------------------ launch
extern "C" void kernel_launch(void* const* d_in, const int* in_sizes, int n_in,
                              void* d_out, int out_size, void* d_ws, size_t ws_size,
                              hipStream_t stream) {
  const float* images  = (const float*)d_in[0];
  const int*   caps    = (const int*)d_in[1];
  const float* W_img   = (const float*)d_in[3];
  const float* b_img   = (const float*)d_in[4];
  const float* W_glob  = (const float*)d_in[5];
  const float* b_glob  = (const float*)d_in[6];
  const float* W_ih1   = (const float*)d_in[7];
  const float* W_hh1   = (const float*)d_in[8];
  const float* b_ih1   = (const float*)d_in[9];
  const float* b_hh1   = (const float*)d_in[10];
  const float* Wx_gate = (const float*)d_in[11];
  const float* bx_gate = (const float*)d_in[12];
  const float* Wh_gate = (const float*)d_in[13];
  const float* bh_gate = (const float*)d_in[14];
  const float* W_ih2   = (const float*)d_in[15];
  const float* W_hh2   = (const float*)d_in[16];
  const float* b_ih2   = (const float*)d_in[17];
  const float* b_hh2   = (const float*)d_in[18];
  const float* Wv      = (const float*)d_in[19];
  const float* bv      = (const float*)d_in[20];
  const float* Ws_     = (const float*)d_in[21];
  const float* bs_     = (const float*)d_in[22];
  const float* Wg      = (const float*)d_in[23];
  const float* wh      = (const float*)d_in[24];
  const float* emb     = (const float*)d_in[25];
  const float* W_fc    = (const float*)d_in[26];
  const float* b_fc    = (const float*)d_in[27];

  float* out = (float*)d_out;
  float* out_alphas = out + (size_t)kB * kT * kV;
  float* out_betas  = out_alphas + (size_t)kB * kT * kP;

  char* base = (char*)d_ws;
  auto alloc = [&](size_t bytes) {
    char* p = base;
    base += (bytes + 255) & ~(size_t)255;
    return p;
  };
  float*          Vfeat   = (float*)alloc((size_t)kB * kP * kH * 4);
  __hip_bfloat16* Vfeatb  = (__hip_bfloat16*)alloc((size_t)kB * kP * kH * 2);
  __hip_bfloat16* imagesb = (__hip_bfloat16*)alloc((size_t)kB * kP * kRaw * 2);
  __hip_bfloat16* WTg1    = (__hip_bfloat16*)alloc((size_t)5120 * 3072 * 2);
  __hip_bfloat16* WTg2    = (__hip_bfloat16*)alloc((size_t)4096 * 3072 * 2);
  __hip_bfloat16* WTfc    = (__hip_bfloat16*)alloc((size_t)12032 * 1024 * 2);
  __hip_bfloat16* WTimg   = (__hip_bfloat16*)alloc((size_t)1024 * 2048 * 2);
  __hip_bfloat16* WTglob  = (__hip_bfloat16*)alloc((size_t)512 * 1024 * 2);
  __hip_bfloat16* WTv     = (__hip_bfloat16*)alloc((size_t)64 * 1024 * 2);
  __hip_bfloat16* wembb   = (__hip_bfloat16*)alloc((size_t)kB * kT * kE * 2);
  float*          img_proj= (float*)alloc((size_t)kB * kP * kP * 4);
  __hip_bfloat16* globb   = (__hip_bfloat16*)alloc((size_t)kB * kE * 2);
  __hip_bfloat16* meanVb  = (__hip_bfloat16*)alloc((size_t)kB * kH * 2);
  float*          c1      = (float*)alloc((size_t)2 * kB * kH * 4);  // c1, c2
  float*          c2      = c1 + kB * kH;
  __hip_bfloat16* h1b     = (__hip_bfloat16*)alloc((size_t)2 * kB * kH * 2);
  __hip_bfloat16* h2b     = h1b + kB * kH;
  float*          g1out   = (float*)alloc((size_t)kB * 5120 * 4);
  float*          chat    = (float*)alloc((size_t)kB * kH * 4);
  __hip_bfloat16* chatb   = (__hip_bfloat16*)alloc((size_t)kB * kH * 2);
  __hip_bfloat16* sbufb   = (__hip_bfloat16*)alloc((size_t)kB * kH * 2);
  float*          bias_g1 = (float*)alloc(5120 * 4);
  float*          bias_g2 = (float*)alloc(4096 * 4);

  // ---- once-per-call prep
  zero_f32<<<(2 * kB * kH + 255) / 256, 256, 0, stream>>>(c1, 2 * kB * kH);
  zero_bf16<<<(2 * kB * kH + 255) / 256, 256, 0, stream>>>(h1b, 2 * kB * kH);
  {
    int n4 = kB * kP * kRaw / 4;
    f32_to_bf16<<<(n4 + 255) / 256, 256, 0, stream>>>(images, imagesb, n4);
  }
  auto T = [&](const float* src, int ldsrc, int K, int N, __hip_bfloat16* dst, int lddst,
               int koff, int noff) {
    transpose_to_bf16<<<dim3((N + 31) / 32, (K + 31) / 32), 256, 0, stream>>>(
        src, ldsrc, K, N, dst, lddst, koff, noff);
  };
  T(W_img,   kH,     kRaw, kH,     WTimg,  kRaw, 0, 0);
  T(W_glob,  kE,     kH,   kE,     WTglob, kH,   0, 0);
  zero_bf16<<<(64 * 1024 + 255) / 256, 256, 0, stream>>>(WTv, 64 * 1024);
  T(Wv,      kP,     kH,   kP,     WTv,    kH,   0, 0);
  T(W_ih1,   4 * kH, 2048, 4 * kH, WTg1,   3072, 0, 0);
  T(W_hh1,   4 * kH, 1024, 4 * kH, WTg1,   3072, 2048, 0);
  T(Wx_gate, kH,     2048, kH,     WTg1,   3072, 0, 4096);
  T(Wh_gate, kH,     1024, kH,     WTg1,   3072, 2048, 4096);
  T(W_ih2,   4 * kH, 2048, 4 * kH, WTg2,   3072, 0, 0);
  T(W_hh2,   4 * kH, 1024, 4 * kH, WTg2,   3072, 2048, 0);
  T(W_fc,    kV,     kH,   kV,     WTfc,   kH,   0, 0);
  zero_bf16<<<(32 * 1024 + 255) / 256, 256, 0, stream>>>(WTfc + (size_t)12000 * 1024, 32 * 1024);
  pack_biases<<<20, 256, 0, stream>>>(b_ih1, b_hh1, bx_gate, bh_gate, b_ih2, b_hh2,
                                      bias_g1, bias_g2);
  gather_emb<<<(kB * kT * kE + 255) / 256, 256, 0, stream>>>(caps, emb, wembb);

  // Vfeat = relu(images @ W_img + b_img)   [4608 x 1024], K=2048
  {
    GemmBArgs ga = {};
    ga.seg[0] = {imagesb, kRaw, 0, kRaw};
    ga.nseg = 1; ga.WT = WTimg; ga.ldk = kRaw; ga.bias = b_img;
    ga.C = Vfeat; ga.C16 = Vfeatb; ga.ldc = kH; ga.N = kH; ga.Ktot = kRaw; ga.act = 1;
    gemm_bf16<<<dim3(kH / 64, kB * kP / 64), 256, 0, stream>>>(ga);
  }
  mean_p<<<(kB * kH + 255) / 256, 256, 0, stream>>>(Vfeat, meanVb);
  // glob = relu(meanV @ W_glob + b_glob)   [128 x 512], K=1024 (bf16 out only)
  {
    GemmBArgs ga = {};
    ga.seg[0] = {meanVb, kH, 0, kH};
    ga.nseg = 1; ga.WT = WTglob; ga.ldk = kH; ga.bias = b_glob;
    ga.C = nullptr; ga.C16 = globb; ga.ldc = kE; ga.N = kE; ga.Ktot = kH; ga.act = 1;
    gemm_bf16<<<dim3(kE / 64, kB / 64), 256, 0, stream>>>(ga);
  }
  // img_proj = Vfeat @ Wv + bv   [4608 x 36], K=1024
  {
    GemmBArgs ga = {};
    ga.seg[0] = {Vfeatb, kH, 0, kH};
    ga.nseg = 1; ga.WT = WTv; ga.ldk = kH; ga.bias = bv;
    ga.C = img_proj; ga.C16 = nullptr; ga.ldc = kP; ga.N = kP; ga.Ktot = kH; ga.act = 0;
    gemm_bf16<<<dim3(1, kB * kP / 64), 256, 0, stream>>>(ga);
  }

  // ---- 20 decode steps
  for (int t = 0; t < kT; ++t) {
    {  // g1 + sentinel: [128 x 5120], K = 3072
      GemmBArgs ga = {};
      ga.seg[0] = {h2b, kH, 0, kH};
      ga.seg[1] = {globb, kE, kH, kH + kE};
      ga.seg[2] = {wembb + (size_t)t * kE, kT * kE, kH + kE, 2048};
      ga.seg[3] = {h1b, kH, 2048, 3072};
      ga.nseg = 4; ga.WT = WTg1; ga.ldk = 3072; ga.bias = bias_g1;
      ga.C = g1out; ga.C16 = nullptr; ga.ldc = 5120; ga.N = 5120; ga.Ktot = 3072; ga.act = 0;
      gemm_bf16<<<dim3(5120 / 64, kB / 64), 256, 0, stream>>>(ga);
    }
    step1_fused<<<kB, 256, 0, stream>>>(g1out, c1, h1b, img_proj, Vfeat,
                                        Wg, Ws_, bs_, wh, chat, chatb,
                                        out_alphas, out_betas, t);
    {  // g2: [128 x 4096], K = 3072
      GemmBArgs ga = {};
      ga.seg[0] = {chatb, kH, 0, kH};
      ga.seg[1] = {h1b, kH, kH, 2048};
      ga.seg[2] = {h2b, kH, 2048, 3072};
      ga.nseg = 3; ga.WT = WTg2; ga.ldk = 3072; ga.bias = bias_g2;
      ga.C = g1out; ga.C16 = nullptr; ga.ldc = 4096; ga.N = 4096; ga.Ktot = 3072; ga.act = 0;
      gemm_bf16<<<dim3(4096 / 64, kB / 64), 256, 0, stream>>>(ga);
    }
    lstm2_elem<<<(kB * kH + 255) / 256, 256, 0, stream>>>(g1out, c2, h2b, chat, sbufb);
    {  // fc: [128 x 12000], K = 1024
      GemmBArgs ga = {};
      ga.seg[0] = {sbufb, kH, 0, kH};
      ga.nseg = 1; ga.WT = WTfc; ga.ldk = kH; ga.bias = b_fc;
      ga.C = out + (size_t)t * kV; ga.C16 = nullptr; ga.ldc = kT * kV; ga.N = kV; ga.Ktot = kH; ga.act = 0;
      gemm_bf16<<<dim3(12032 / 64, kB / 64), 256, 0, stream>>>(ga);
    }
  }
}